// Round 4
// baseline (6461.427 us; speedup 1.0000x reference)
//
#include <hip/hip_runtime.h>
#include <hip/hip_fp16.h>

#define T_LEN 4096
#define START_TAG 14
#define STOP_TAG 15
#define NEG_VAL -10000.0f

typedef unsigned int u32;
typedef unsigned short u16;
typedef unsigned long long u64;

// ---------- ws layout (bytes) ----------
#define GX_OFF      0u              // __half [4096][2048]  (dir*1024 + d*4 + gate)
#define OUT_OFF     16777216u       // float  [4096][512]
#define LOGITS_OFF  25165824u       // float  [4096]
#define ALPHAS_OFF  25182208u       // float  [4096]
#define FEATS_OFF   25198592u       // float  [4096][16]
#define CMAT_OFF    25460736u       // float  [128][16][16]
#define VIN_OFF     25591808u       // float  [128][16]
#define BP_OFF      25600000u       // u32    [4096][2]
#define BMAP_OFF    25632768u       // u32    [128][16]
#define STAIL_OFF   25640960u       // u32    [128][16]
#define BEST_OFF    25649152u       // u32    [1]

__device__ __forceinline__ int sdot4(u32 a, u32 b, int c) {
#if __has_builtin(__builtin_amdgcn_sdot4)
  return __builtin_amdgcn_sdot4((int)a, (int)b, c, false);
#else
  c += (int)(signed char)(a & 0xff)         * (int)(signed char)(b & 0xff);
  c += (int)(signed char)((a >> 8) & 0xff)  * (int)(signed char)((b >> 8) & 0xff);
  c += (int)(signed char)((a >> 16) & 0xff) * (int)(signed char)((b >> 16) & 0xff);
  c += (int)(signed char)((a >> 24) & 0xff) * (int)(signed char)((b >> 24) & 0xff);
  return c;
#endif
}

__device__ __forceinline__ u32 packq(int q0, int q1, int q2, int q3) {
  return (u32)(q0 & 255) | ((u32)(q1 & 255) << 8) |
         ((u32)(q2 & 255) << 16) | ((u32)(q3 & 255) << 24);
}

__device__ __forceinline__ float sigm(float x) {
  return __builtin_amdgcn_rcpf(1.f + __expf(-x));
}
__device__ __forceinline__ float tanh_fast(float x) {
  float e = __expf(-2.f * fabsf(x));
  float r = (1.f - e) * __builtin_amdgcn_rcpf(1.f + e);
  return copysignf(r, x);
}

// ---------------------------------------------------------------------------
__global__ void prep_kernel(float* logits) {
  const int i = threadIdx.x + blockIdx.x * 1024;
  if (i < 4096) logits[i] = 0.f;
}

// ---------------------------------------------------------------------------
// Gx[t][dir*1024 + d*4 + gate] = emb[sentence[t]] . Whh-row + bih + bhh
// (gate-interleaved so the lstm kernel loads one uint2 per thread per step)
__global__ __launch_bounds__(256) void gx_kernel(
    const int* __restrict__ sentence, const float* __restrict__ emb,
    const float* __restrict__ Wih_f, const float* __restrict__ Wih_b,
    const float* __restrict__ bih_f, const float* __restrict__ bhh_f,
    const float* __restrict__ bih_b, const float* __restrict__ bhh_b,
    __half* __restrict__ Gx)
{
  __shared__ float ws[32][260];
  const int r0 = blockIdx.x * 32;
  const int t0 = blockIdx.y * 32;
  const int tid = threadIdx.x;
  {
    const int c4 = (tid & 63) * 4;
    const int rA = tid >> 6;
    #pragma unroll
    for (int p = 0; p < 8; ++p) {
      const int rr = rA + p * 4;
      const int R = r0 + rr;
      const float* src = (R < 1024) ? (Wih_f + (size_t)R * 256 + c4)
                                    : (Wih_b + (size_t)(R - 1024) * 256 + c4);
      *(float4*)&ws[rr][c4] = *(const float4*)src;
    }
  }
  __syncthreads();
  const int ttb = tid >> 4, rgb = tid & 15;
  const int s0r = sentence[t0 + ttb];
  const int s1r = sentence[t0 + ttb + 16];
  const float* x0p = emb + (size_t)s0r * 256;
  const float* x1p = emb + (size_t)s1r * 256;
  float acc00 = 0, acc01 = 0, acc10 = 0, acc11 = 0;
  #pragma unroll 4
  for (int c4 = 0; c4 < 256; c4 += 4) {
    float4 x0 = *(const float4*)(x0p + c4);
    float4 x1 = *(const float4*)(x1p + c4);
    float4 w0 = *(const float4*)&ws[rgb][c4];
    float4 w1 = *(const float4*)&ws[rgb + 16][c4];
    acc00 += x0.x*w0.x + x0.y*w0.y + x0.z*w0.z + x0.w*w0.w;
    acc01 += x0.x*w1.x + x0.y*w1.y + x0.z*w1.z + x0.w*w1.w;
    acc10 += x1.x*w0.x + x1.y*w0.y + x1.z*w0.z + x1.w*w0.w;
    acc11 += x1.x*w1.x + x1.y*w1.y + x1.z*w1.z + x1.w*w1.w;
  }
  #pragma unroll
  for (int ri = 0; ri < 2; ++ri) {
    const int R = r0 + rgb + ri * 16;
    const int dir = R >> 10, grow = R & 1023;
    const int gate = grow >> 8, dd = grow & 255;
    const float bias = dir ? (bih_b[grow] + bhh_b[grow])
                           : (bih_f[grow] + bhh_f[grow]);
    const float a0 = ri ? acc01 : acc00;
    const float a1 = ri ? acc11 : acc10;
    const size_t off = (size_t)dir * 1024 + dd * 4 + gate;
    Gx[(size_t)(t0 + ttb) * 2048 + off]      = __float2half(a0 + bias);
    Gx[(size_t)(t0 + ttb + 16) * 2048 + off] = __float2half(a1 + bias);
  }
}

// ---------------------------------------------------------------------------
// Recurrence v4: grid=2 (dir), 256 threads (4 waves). Thread = column d,
// owns ALL FOUR gate rows {d, 256+d, 512+d, 768+d} of Whh (int8, 256 VGPRs).
// Per step: 16 broadcast ds_read_b128 of h (amortized over 4 rows), 256
// sdot4, activations + c/h update entirely thread-local (no shuffles),
// one barrier. h int8 parity-double-buffered in LDS; h history fp16 in LDS
// flushed every 128 steps.
__global__ __launch_bounds__(256, 1) void lstm_kernel(
    const float* __restrict__ Whh_f, const float* __restrict__ Whh_b,
    const float* __restrict__ h0, const float* __restrict__ c0,
    const __half* __restrict__ Gx, float* __restrict__ out_lstm)
{
  const int dir = blockIdx.x;
  const int d = threadIdx.x;
  const float* Whh = dir ? Whh_b : Whh_f;

  __shared__ __align__(16) u32 hq[2][64];       // int8 h, parity buffers
  __shared__ __align__(16) u16 hist[128 * 256]; // 64 KB fp16 h history

  // ---- load + quantize the 4 owned weight rows (pass2 hits L1/L2) ----
  u32 w8[256];
  float fs0, fs1, fs2, fs3;
  {
    float fsk[4];
    #pragma unroll
    for (int g = 0; g < 4; ++g) {
      const float4* wr = (const float4*)(Whh + (size_t)(g * 256 + d) * 256);
      float mx = 1e-10f;
      #pragma unroll 8
      for (int j = 0; j < 64; ++j) {
        float4 f = wr[j];
        mx = fmaxf(mx, fmaxf(fmaxf(fabsf(f.x), fabsf(f.y)),
                             fmaxf(fabsf(f.z), fabsf(f.w))));
      }
      const float qs = 127.f / mx;
      fsk[g] = mx * (1.f / (127.f * 32.f));   // w-scale * h-scale(1/32)
      #pragma unroll
      for (int j = 0; j < 64; ++j) {
        float4 f = wr[j];
        w8[g * 64 + j] = packq((int)rintf(f.x * qs), (int)rintf(f.y * qs),
                               (int)rintf(f.z * qs), (int)rintf(f.w * qs));
      }
    }
    fs0 = fsk[0]; fs1 = fsk[1]; fs2 = fsk[2]; fs3 = fsk[3];
  }

  float creg = c0[dir * 256 + d];
  {
    float hv = h0[dir * 256 + d];
    int q = max(-127, min(127, (int)rintf(hv * 32.f)));
    ((signed char*)&hq[0][0])[d] = (signed char)q;
  }
  const u16* GxU = (const u16*)Gx;
  const int t0i = dir ? (T_LEN - 1) : 0;
  uint2 gx = *(const uint2*)(GxU + (size_t)t0i * 2048 + dir * 1024 + 4 * d);
  __syncthreads();

  for (int s = 0; s < T_LEN; ++s) {
    // prefetch next step's Gx first — a full step (~900 cyc) to land
    uint2 gn = make_uint2(0u, 0u);
    if (s + 1 < T_LEN) {
      const int tn = dir ? (T_LEN - 2 - s) : (s + 1);
      gn = *(const uint2*)(GxU + (size_t)tn * 2048 + dir * 1024 + 4 * d);
    }
    // 256-col int8 dot x 4 gate rows, broadcast LDS reads
    const uint4* hp = (const uint4*)&hq[s & 1][0];
    int a0 = 0, a1 = 0, a2 = 0, a3 = 0;
    #pragma unroll
    for (int j = 0; j < 16; ++j) {
      uint4 hv = hp[j];
      a0 = sdot4(w8[4 * j + 0], hv.x, a0);
      a0 = sdot4(w8[4 * j + 1], hv.y, a0);
      a0 = sdot4(w8[4 * j + 2], hv.z, a0);
      a0 = sdot4(w8[4 * j + 3], hv.w, a0);
      a1 = sdot4(w8[64 + 4 * j + 0], hv.x, a1);
      a1 = sdot4(w8[64 + 4 * j + 1], hv.y, a1);
      a1 = sdot4(w8[64 + 4 * j + 2], hv.z, a1);
      a1 = sdot4(w8[64 + 4 * j + 3], hv.w, a1);
      a2 = sdot4(w8[128 + 4 * j + 0], hv.x, a2);
      a2 = sdot4(w8[128 + 4 * j + 1], hv.y, a2);
      a2 = sdot4(w8[128 + 4 * j + 2], hv.z, a2);
      a2 = sdot4(w8[128 + 4 * j + 3], hv.w, a2);
      a3 = sdot4(w8[192 + 4 * j + 0], hv.x, a3);
      a3 = sdot4(w8[192 + 4 * j + 1], hv.y, a3);
      a3 = sdot4(w8[192 + 4 * j + 2], hv.z, a3);
      a3 = sdot4(w8[192 + 4 * j + 3], hv.w, a3);
    }
    const float gi = (float)a0 * fs0 + __half2float(__ushort_as_half((u16)(gx.x & 0xffff)));
    const float gf = (float)a1 * fs1 + __half2float(__ushort_as_half((u16)(gx.x >> 16)));
    const float gg = (float)a2 * fs2 + __half2float(__ushort_as_half((u16)(gx.y & 0xffff)));
    const float go = (float)a3 * fs3 + __half2float(__ushort_as_half((u16)(gx.y >> 16)));
    gx = gn;
    const float iv = sigm(gi);
    const float fv = sigm(gf);
    const float gv = tanh_fast(gg);
    const float ov = sigm(go);
    creg = __builtin_fmaf(fv, creg, iv * gv);
    const float h = ov * tanh_fast(creg);
    hist[(s & 127) * 256 + d] = __half_as_ushort(__float2half(h));
    {
      int q = max(-127, min(127, (int)rintf(h * 32.f)));
      ((signed char*)&hq[(s + 1) & 1][0])[d] = (signed char)q;
    }
    __syncthreads();
    if ((s & 127) == 127) {   // flush fp16 history -> out_lstm
      const int sbase = s - 127;
      #pragma unroll 4
      for (int i = 0; i < 32; ++i) {
        const int idx = d + i * 256;           // u64 index into hist
        const int step = idx >> 6, d0 = (idx & 63) * 4;
        const int tt = sbase + step;
        const int tg = dir ? (T_LEN - 1 - tt) : tt;
        uint2 hv = ((const uint2*)hist)[idx];
        float4 ov4;
        ov4.x = __half2float(__ushort_as_half((u16)(hv.x & 0xffff)));
        ov4.y = __half2float(__ushort_as_half((u16)(hv.x >> 16)));
        ov4.z = __half2float(__ushort_as_half((u16)(hv.y & 0xffff)));
        ov4.w = __half2float(__ushort_as_half((u16)(hv.y >> 16)));
        *(float4*)&out_lstm[(size_t)tg * 512 + dir * 256 + d0] = ov4;
      }
      __syncthreads();
    }
  }
}

// ---------------------------------------------------------------------------
__global__ __launch_bounds__(256) void attn_kernel(
    const float* __restrict__ out_lstm, const float* __restrict__ w_omega,
    const float* __restrict__ u_omega, float* __restrict__ logits)
{
  __shared__ float bst[32][132];
  const int c0 = blockIdx.x * 32;
  const int t0 = blockIdx.y * 32;
  const int tid = threadIdx.x;
  const int ttb = tid >> 4, cgb = tid & 15;
  const float* a0p = out_lstm + (size_t)(t0 + ttb) * 512;
  const float* a1p = out_lstm + (size_t)(t0 + ttb + 16) * 512;
  float acc00 = 0, acc01 = 0, acc10 = 0, acc11 = 0;
  for (int kh = 0; kh < 4; ++kh) {
    __syncthreads();
    {
      const int cc = tid & 31;
      const int kA = tid >> 5;
      #pragma unroll
      for (int p = 0; p < 16; ++p) {
        const int kkx = kA + p * 8;
        bst[cc][kkx] = w_omega[(size_t)(kh * 128 + kkx) * 512 + c0 + cc];
      }
    }
    __syncthreads();
    #pragma unroll 4
    for (int k4 = 0; k4 < 128; k4 += 4) {
      float4 a0 = *(const float4*)(a0p + kh * 128 + k4);
      float4 a1 = *(const float4*)(a1p + kh * 128 + k4);
      float4 b0 = *(const float4*)&bst[cgb][k4];
      float4 b1 = *(const float4*)&bst[cgb + 16][k4];
      acc00 += a0.x*b0.x + a0.y*b0.y + a0.z*b0.z + a0.w*b0.w;
      acc01 += a0.x*b1.x + a0.y*b1.y + a0.z*b1.z + a0.w*b1.w;
      acc10 += a1.x*b0.x + a1.y*b0.y + a1.z*b0.z + a1.w*b0.w;
      acc11 += a1.x*b1.x + a1.y*b1.y + a1.z*b1.z + a1.w*b1.w;
    }
  }
  const float u0 = u_omega[c0 + cgb], u1 = u_omega[c0 + 16 + cgb];
  float s0 = tanh_fast(acc00) * u0 + tanh_fast(acc01) * u1;
  float s1 = tanh_fast(acc10) * u0 + tanh_fast(acc11) * u1;
  #pragma unroll
  for (int msk = 1; msk < 16; msk <<= 1) {
    s0 += __shfl_xor(s0, msk);
    s1 += __shfl_xor(s1, msk);
  }
  if (cgb == 0) {
    atomicAdd(&logits[t0 + ttb], s0);
    atomicAdd(&logits[t0 + ttb + 16], s1);
  }
}

// ---------------------------------------------------------------------------
__global__ __launch_bounds__(1024) void softmax_kernel(
    const float* __restrict__ logits, float* __restrict__ alphas)
{
  __shared__ float red[1024];
  const int tid = threadIdx.x;
  float l0 = logits[tid], l1 = logits[1024 + tid];
  float l2 = logits[2048 + tid], l3 = logits[3072 + tid];
  red[tid] = fmaxf(fmaxf(l0, l1), fmaxf(l2, l3));
  __syncthreads();
  for (int s = 512; s > 0; s >>= 1) {
    if (tid < s) red[tid] = fmaxf(red[tid], red[tid + s]);
    __syncthreads();
  }
  const float gm = red[0];
  __syncthreads();
  float e0 = __expf(l0 - gm), e1 = __expf(l1 - gm);
  float e2 = __expf(l2 - gm), e3 = __expf(l3 - gm);
  red[tid] = e0 + e1 + e2 + e3;
  __syncthreads();
  for (int s = 512; s > 0; s >>= 1) {
    if (tid < s) red[tid] += red[tid + s];
    __syncthreads();
  }
  const float inv = 1.0f / red[0];
  alphas[tid] = e0 * inv; alphas[1024 + tid] = e1 * inv;
  alphas[2048 + tid] = e2 * inv; alphas[3072 + tid] = e3 * inv;
}

// ---------------------------------------------------------------------------
__global__ __launch_bounds__(256) void feats_kernel(
    const float* __restrict__ out_lstm, const float* __restrict__ W_tag,
    const float* __restrict__ b_tag, const float* __restrict__ alphas,
    float* __restrict__ feats)
{
  __shared__ float wt[16][516];
  const int t0 = blockIdx.x * 16;
  const int tid = threadIdx.x;
  {
    const int k4 = (tid & 127) * 4;
    const int gA = tid >> 7;
    #pragma unroll
    for (int p = 0; p < 8; ++p) {
      const int tg = gA + p * 2;
      *(float4*)&wt[tg][k4] = *(const float4*)(W_tag + (size_t)tg * 512 + k4);
    }
  }
  __syncthreads();
  const int tt = tid >> 4, tg = tid & 15;
  const float* ap = out_lstm + (size_t)(t0 + tt) * 512;
  float acc = 0.f;
  #pragma unroll 4
  for (int k4 = 0; k4 < 512; k4 += 4) {
    float4 a = *(const float4*)(ap + k4);
    float4 b = *(const float4*)&wt[tg][k4];
    acc += a.x*b.x + a.y*b.y + a.z*b.z + a.w*b.w;
  }
  feats[(size_t)(t0 + tt) * 16 + tg] = acc * alphas[t0 + tt] + b_tag[tg];
}

// ---------------------------------------------------------------------------
__global__ __launch_bounds__(256) void vit_block_mats(
    const float* __restrict__ feats, const float* __restrict__ trans,
    float* __restrict__ Cmat)
{
  __shared__ float C[2][16][17];
  const int b = blockIdx.x;
  const int tid = threadIdx.x;
  const int n = tid >> 4, p = tid & 15;
  float tr[16];
  #pragma unroll
  for (int k = 0; k < 16; ++k) tr[k] = trans[n * 16 + k];
  const int t0 = b * 32;
  C[0][n][p] = tr[p] + feats[t0 * 16 + n];
  float fnext = feats[(t0 + 1) * 16 + n];
  __syncthreads();
  for (int s = 1; s < 32; ++s) {
    const float ft = fnext;
    if (s + 1 < 32) fnext = feats[(t0 + s + 1) * 16 + n];
    const int pr = (s - 1) & 1, cu = s & 1;
    float m = tr[0] + C[pr][0][p];
    #pragma unroll
    for (int k = 1; k < 16; ++k) m = fmaxf(m, tr[k] + C[pr][k][p]);
    C[cu][n][p] = m + ft;
    __syncthreads();
  }
  Cmat[b * 256 + n * 16 + p] = C[1][n][p];
}

__global__ __launch_bounds__(64) void vit_scan(
    const float* __restrict__ Cmat, const float* __restrict__ trans,
    float* __restrict__ v_in, float* __restrict__ d_out, u32* __restrict__ best_ws)
{
  const int l = threadIdx.x;
  const int n = l & 15, pg = l >> 4;
  float v = (n == START_TAG) ? 0.f : NEG_VAL;
  for (int b = 0; b < 128; ++b) {
    if (pg == 0) v_in[b * 16 + n] = v;
    float4 c4 = *(const float4*)&Cmat[b * 256 + n * 16 + pg * 4];
    float cand = c4.x + __shfl(v, pg * 4 + 0);
    cand = fmaxf(cand, c4.y + __shfl(v, pg * 4 + 1));
    cand = fmaxf(cand, c4.z + __shfl(v, pg * 4 + 2));
    cand = fmaxf(cand, c4.w + __shfl(v, pg * 4 + 3));
    cand = fmaxf(cand, __shfl_xor(cand, 16));
    cand = fmaxf(cand, __shfl_xor(cand, 32));
    v = cand;
  }
  float term = v + trans[STOP_TAG * 16 + n];
  int mi = n;
  #pragma unroll
  for (int msk = 1; msk < 16; msk <<= 1) {
    float om = __shfl_xor(term, msk); int omi = __shfl_xor(mi, msk);
    if (om > term || (om == term && omi < mi)) { term = om; mi = omi; }
  }
  if (l == 0) { d_out[0] = term; *best_ws = (u32)mi; }
}

__global__ __launch_bounds__(64) void vit_bp(
    const float* __restrict__ feats, const float* __restrict__ trans,
    const float* __restrict__ v_in, u32* __restrict__ bp)
{
  const int b = blockIdx.x;
  const int l = threadIdx.x;
  const int n = l & 15, pg = l >> 4;
  const float4 tr4 = *(const float4*)&trans[n * 16 + pg * 4];
  float v = v_in[b * 16 + n];
  const int t0 = b * 32;
  float fcur = feats[t0 * 16 + n];
  for (int s = 0; s < 32; ++s) {
    const int t = t0 + s;
    float fnext = (s + 1 < 32) ? feats[(t + 1) * 16 + n] : 0.f;
    float f0 = __shfl(v, pg * 4 + 0), f1 = __shfl(v, pg * 4 + 1);
    float f2 = __shfl(v, pg * 4 + 2), f3 = __shfl(v, pg * 4 + 3);
    float m = f0 + tr4.x; int mi = pg * 4;
    float c;
    c = f1 + tr4.y; if (c > m) { m = c; mi = pg * 4 + 1; }
    c = f2 + tr4.z; if (c > m) { m = c; mi = pg * 4 + 2; }
    c = f3 + tr4.w; if (c > m) { m = c; mi = pg * 4 + 3; }
    float om; int omi;
    om = __shfl_xor(m, 16); omi = __shfl_xor(mi, 16);
    if (om > m || (om == m && omi < mi)) { m = om; mi = omi; }
    om = __shfl_xor(m, 32); omi = __shfl_xor(mi, 32);
    if (om > m || (om == m && omi < mi)) { m = om; mi = omi; }
    u32 w = (l < 16) ? ((u32)mi << ((n & 7) * 4)) : 0u;
    w |= __shfl_xor(w, 1); w |= __shfl_xor(w, 2); w |= __shfl_xor(w, 4);
    if (l == 0) bp[t * 2] = w;
    if (l == 8) bp[t * 2 + 1] = w;
    v = m + fcur;
    fcur = fnext;
  }
}

__global__ __launch_bounds__(64) void vit_bmap(
    const u32* __restrict__ bp, u32* __restrict__ Bmap)
{
  const int b = blockIdx.x;
  const int l = threadIdx.x;
  if (l >= 16) return;
  int t = b * 32 + 31;
  u32 lo = bp[t * 2], hi = bp[t * 2 + 1];
  int A = (int)(((l < 8 ? lo : hi) >> ((l & 7) * 4)) & 15u);
  for (t = b * 32 + 30; t >= b * 32; --t) {
    lo = bp[t * 2]; hi = bp[t * 2 + 1];
    A = (int)(((A < 8 ? lo : hi) >> ((A & 7) * 4)) & 15u);
  }
  Bmap[b * 16 + l] = (u32)A;
}

__global__ __launch_bounds__(64) void vit_suffix(
    const u32* __restrict__ Bmap, u32* __restrict__ Stail)
{
  __shared__ u32 bm[2048];
  const int l = threadIdx.x;
  for (int i = l; i < 2048; i += 64) bm[i] = Bmap[i];
  __syncthreads();
  if (l < 16) {
    int S = l;
    for (int b = 127; b >= 0; --b) {
      Stail[b * 16 + l] = (u32)S;
      S = (int)bm[b * 16 + S];
    }
  }
}

__global__ __launch_bounds__(64) void vit_emit(
    const u32* __restrict__ bp, const u32* __restrict__ Stail,
    const u32* __restrict__ best_ws, float* __restrict__ d_out)
{
  const int b = blockIdx.x;
  const int l = threadIdx.x;
  const int best = (int)*best_ws;
  int A = (l < 16) ? (int)Stail[b * 16 + l] : 0;
  for (int s = 31; s >= 0; --s) {
    const int t = b * 32 + s;
    const int pv = __shfl(A, best);
    if (l == 0) d_out[1 + t] = (float)pv;
    if (s > 0) {
      const u32 lo = bp[t * 2], hi = bp[t * 2 + 1];
      A = (int)(((A < 8 ? lo : hi) >> ((A & 7) * 4)) & 15u);
    }
  }
}

// ---------------------------------------------------------------------------
extern "C" void kernel_launch(void* const* d_in, const int* in_sizes, int n_in,
                              void* d_out, int out_size, void* d_ws, size_t ws_size,
                              hipStream_t stream)
{
  const int*   sentence = (const int*)  d_in[0];
  const float* emb      = (const float*)d_in[1];
  const float* Wih_f    = (const float*)d_in[2];
  const float* Whh_f    = (const float*)d_in[3];
  const float* bih_f    = (const float*)d_in[4];
  const float* bhh_f    = (const float*)d_in[5];
  const float* Wih_b    = (const float*)d_in[6];
  const float* Whh_b    = (const float*)d_in[7];
  const float* bih_b    = (const float*)d_in[8];
  const float* bhh_b    = (const float*)d_in[9];
  const float* h0       = (const float*)d_in[10];
  const float* c0       = (const float*)d_in[11];
  const float* w_omega  = (const float*)d_in[12];
  const float* u_omega  = (const float*)d_in[13];
  const float* W_tag    = (const float*)d_in[14];
  const float* b_tag    = (const float*)d_in[15];
  const float* trans    = (const float*)d_in[16];

  char* ws = (char*)d_ws;
  __half* Gx      = (__half*)(ws + GX_OFF);
  float* out_lstm = (float*)(ws + OUT_OFF);
  float* logits   = (float*)(ws + LOGITS_OFF);
  float* alphas   = (float*)(ws + ALPHAS_OFF);
  float* feats    = (float*)(ws + FEATS_OFF);
  float* Cmat     = (float*)(ws + CMAT_OFF);
  float* v_in     = (float*)(ws + VIN_OFF);
  u32*   bp       = (u32*)  (ws + BP_OFF);
  u32*   Bmap     = (u32*)  (ws + BMAP_OFF);
  u32*   Stail    = (u32*)  (ws + STAIL_OFF);
  u32*   best_ws  = (u32*)  (ws + BEST_OFF);
  float* out      = (float*)d_out;

  hipLaunchKernelGGL(prep_kernel, dim3(4), dim3(1024), 0, stream, logits);
  hipLaunchKernelGGL(gx_kernel, dim3(64, 128), dim3(256), 0, stream,
                     sentence, emb, Wih_f, Wih_b, bih_f, bhh_f, bih_b, bhh_b, Gx);
  hipLaunchKernelGGL(lstm_kernel, dim3(2), dim3(256), 0, stream,
                     Whh_f, Whh_b, h0, c0, Gx, out_lstm);
  hipLaunchKernelGGL(attn_kernel, dim3(16, 128), dim3(256), 0, stream,
                     out_lstm, w_omega, u_omega, logits);
  hipLaunchKernelGGL(softmax_kernel, dim3(1), dim3(1024), 0, stream, logits, alphas);
  hipLaunchKernelGGL(feats_kernel, dim3(256), dim3(256), 0, stream,
                     out_lstm, W_tag, b_tag, alphas, feats);
  hipLaunchKernelGGL(vit_block_mats, dim3(128), dim3(256), 0, stream,
                     feats, trans, Cmat);
  hipLaunchKernelGGL(vit_scan, dim3(1), dim3(64), 0, stream,
                     Cmat, trans, v_in, out, best_ws);
  hipLaunchKernelGGL(vit_bp, dim3(128), dim3(64), 0, stream,
                     feats, trans, v_in, bp);
  hipLaunchKernelGGL(vit_bmap, dim3(128), dim3(64), 0, stream, bp, Bmap);
  hipLaunchKernelGGL(vit_suffix, dim3(1), dim3(64), 0, stream, Bmap, Stail);
  hipLaunchKernelGGL(vit_emit, dim3(128), dim3(64), 0, stream,
                     bp, Stail, best_ws, out);
}

// Round 5
// 5434.494 us; speedup vs baseline: 1.1890x; 1.1890x over previous
//
#include <hip/hip_runtime.h>
#include <hip/hip_fp16.h>

#define T_LEN 4096
#define START_TAG 14
#define STOP_TAG 15
#define NEG_VAL -10000.0f

typedef unsigned int u32;
typedef unsigned short u16;
typedef unsigned long long u64;

// ---------- ws layout (bytes) ----------
#define GX_OFF      0u              // __half [4096][2048]  (dir*1024 + d*4 + gate)
#define OUT_OFF     16777216u       // float  [4096][512]
#define LOGITS_OFF  25165824u       // float  [4096]
#define ALPHAS_OFF  25182208u       // float  [4096]
#define FEATS_OFF   25198592u       // float  [4096][16]
#define CMAT_OFF    25460736u       // float  [128][16][16]
#define VIN_OFF     25591808u       // float  [128][16]
#define BP_OFF      25600000u       // u32    [4096][2]
#define BMAP_OFF    25632768u       // u32    [128][16]
#define STAIL_OFF   25640960u       // u32    [128][16]
#define BEST_OFF    25649152u       // u32    [1]

__device__ __forceinline__ int sdot4(u32 a, u32 b, int c) {
#if __has_builtin(__builtin_amdgcn_sdot4)
  return __builtin_amdgcn_sdot4((int)a, (int)b, c, false);
#else
  c += (int)(signed char)(a & 0xff)         * (int)(signed char)(b & 0xff);
  c += (int)(signed char)((a >> 8) & 0xff)  * (int)(signed char)((b >> 8) & 0xff);
  c += (int)(signed char)((a >> 16) & 0xff) * (int)(signed char)((b >> 16) & 0xff);
  c += (int)(signed char)((a >> 24) & 0xff) * (int)(signed char)((b >> 24) & 0xff);
  return c;
#endif
}

__device__ __forceinline__ u32 packq(int q0, int q1, int q2, int q3) {
  return (u32)(q0 & 255) | ((u32)(q1 & 255) << 8) |
         ((u32)(q2 & 255) << 16) | ((u32)(q3 & 255) << 24);
}

__device__ __forceinline__ float sigm(float x) {
  return __builtin_amdgcn_rcpf(1.f + __expf(-x));
}
__device__ __forceinline__ float tanh_fast(float x) {
  float e = __expf(-2.f * fabsf(x));
  float r = (1.f - e) * __builtin_amdgcn_rcpf(1.f + e);
  return copysignf(r, x);
}

// ---------------------------------------------------------------------------
__global__ void prep_kernel(float* logits) {
  const int i = threadIdx.x + blockIdx.x * 1024;
  if (i < 4096) logits[i] = 0.f;
}

// ---------------------------------------------------------------------------
// Gx[t][dir*1024 + d*4 + gate] = emb[sentence[t]] . W-row + bih + bhh
__global__ __launch_bounds__(256) void gx_kernel(
    const int* __restrict__ sentence, const float* __restrict__ emb,
    const float* __restrict__ Wih_f, const float* __restrict__ Wih_b,
    const float* __restrict__ bih_f, const float* __restrict__ bhh_f,
    const float* __restrict__ bih_b, const float* __restrict__ bhh_b,
    __half* __restrict__ Gx)
{
  __shared__ float ws[32][260];
  const int r0 = blockIdx.x * 32;
  const int t0 = blockIdx.y * 32;
  const int tid = threadIdx.x;
  {
    const int c4 = (tid & 63) * 4;
    const int rA = tid >> 6;
    #pragma unroll
    for (int p = 0; p < 8; ++p) {
      const int rr = rA + p * 4;
      const int R = r0 + rr;
      const float* src = (R < 1024) ? (Wih_f + (size_t)R * 256 + c4)
                                    : (Wih_b + (size_t)(R - 1024) * 256 + c4);
      *(float4*)&ws[rr][c4] = *(const float4*)src;
    }
  }
  __syncthreads();
  const int ttb = tid >> 4, rgb = tid & 15;
  const int s0r = sentence[t0 + ttb];
  const int s1r = sentence[t0 + ttb + 16];
  const float* x0p = emb + (size_t)s0r * 256;
  const float* x1p = emb + (size_t)s1r * 256;
  float acc00 = 0, acc01 = 0, acc10 = 0, acc11 = 0;
  #pragma unroll 4
  for (int c4 = 0; c4 < 256; c4 += 4) {
    float4 x0 = *(const float4*)(x0p + c4);
    float4 x1 = *(const float4*)(x1p + c4);
    float4 w0 = *(const float4*)&ws[rgb][c4];
    float4 w1 = *(const float4*)&ws[rgb + 16][c4];
    acc00 += x0.x*w0.x + x0.y*w0.y + x0.z*w0.z + x0.w*w0.w;
    acc01 += x0.x*w1.x + x0.y*w1.y + x0.z*w1.z + x0.w*w1.w;
    acc10 += x1.x*w0.x + x1.y*w0.y + x1.z*w0.z + x1.w*w0.w;
    acc11 += x1.x*w1.x + x1.y*w1.y + x1.z*w1.z + x1.w*w1.w;
  }
  #pragma unroll
  for (int ri = 0; ri < 2; ++ri) {
    const int R = r0 + rgb + ri * 16;
    const int dir = R >> 10, grow = R & 1023;
    const int gate = grow >> 8, dd = grow & 255;
    const float bias = dir ? (bih_b[grow] + bhh_b[grow])
                           : (bih_f[grow] + bhh_f[grow]);
    const float a0 = ri ? acc01 : acc00;
    const float a1 = ri ? acc11 : acc10;
    const size_t off = (size_t)dir * 1024 + dd * 4 + gate;
    Gx[(size_t)(t0 + ttb) * 2048 + off]      = __float2half(a0 + bias);
    Gx[(size_t)(t0 + ttb + 16) * 2048 + off] = __float2half(a1 + bias);
  }
}

// ---------------------------------------------------------------------------
// Recurrence v5: grid=2 (dir), 512 threads (8 waves, 2/SIMD). Thread =
// (column d = tid&255, gate-pair pp = tid>>8): rows {2pp*256+d, (2pp+1)*256+d}
// as int8 in 128 arch VGPRs (NO AGPRs: 256-reg cap respected).
// h broadcast: ONE ds_read_b32 per wave (lane i <- h-word i), then
// v_readlane -> SGPR feeding sdot4 (VOP3P takes 1 SGPR src) — kills the
// round-3 LDS-pipe ceiling (3072 -> ~50 cyc/step).
// Gate exchange (g,o -> i,f thread) via 2KB LDS; 2 barriers/step.
__global__ __launch_bounds__(512, 2) void lstm_kernel(
    const float* __restrict__ Whh_f, const float* __restrict__ Whh_b,
    const float* __restrict__ h0, const float* __restrict__ c0,
    const __half* __restrict__ Gx, float* __restrict__ out_lstm)
{
  const int dir = blockIdx.x;
  const int t = threadIdx.x;
  const int d = t & 255, pp = t >> 8;
  const int lane = t & 63;
  const float* Whh = dir ? Whh_b : Whh_f;

  __shared__ __align__(16) u32 hq[2][64];       // int8 h, parity buffers
  __shared__ float2 xch[256];                   // (gv, ov) exchange
  __shared__ __align__(16) u16 hist[128 * 256]; // 64 KB fp16 h history

  // ---- load + quantize the 2 owned weight rows ----
  u32 w8[128];
  float fs0, fs1;
  {
    float fsk[2];
    #pragma unroll
    for (int r = 0; r < 2; ++r) {
      const float4* wr = (const float4*)(Whh + (size_t)((2 * pp + r) * 256 + d) * 256);
      float mx = 1e-10f;
      #pragma unroll 8
      for (int j = 0; j < 64; ++j) {
        float4 f = wr[j];
        mx = fmaxf(mx, fmaxf(fmaxf(fabsf(f.x), fabsf(f.y)),
                             fmaxf(fabsf(f.z), fabsf(f.w))));
      }
      const float qs = 127.f / mx;
      fsk[r] = mx * (1.f / (127.f * 32.f));   // w-scale * h-scale(1/32)
      #pragma unroll
      for (int j = 0; j < 64; ++j) {
        float4 f = wr[j];
        w8[r * 64 + j] = packq((int)rintf(f.x * qs), (int)rintf(f.y * qs),
                               (int)rintf(f.z * qs), (int)rintf(f.w * qs));
      }
    }
    fs0 = fsk[0]; fs1 = fsk[1];
  }

  float creg = 0.f;
  if (pp == 0) {
    creg = c0[dir * 256 + d];
    float hv = h0[dir * 256 + d];
    int q = max(-127, min(127, (int)rintf(hv * 32.f)));
    int q1 = __shfl_down(q, 1), q2 = __shfl_down(q, 2), q3 = __shfl_down(q, 3);
    if ((d & 3) == 0) hq[0][d >> 2] = packq(q, q1, q2, q3);
  }
  const u32* GxW = (const u32*)Gx;
  const int t0i = dir ? (T_LEN - 1) : 0;
  u32 gx = GxW[(size_t)t0i * 1024 + dir * 512 + d * 2 + pp];
  __syncthreads();

  for (int s = 0; s < T_LEN; ++s) {
    // prefetch next step's Gx (lands well before the barrier drain)
    u32 gn = 0u;
    if (s + 1 < T_LEN) {
      const int tn = dir ? (T_LEN - 2 - s) : (s + 1);
      gn = GxW[(size_t)tn * 1024 + dir * 512 + d * 2 + pp];
    }
    // one broadcast LDS read per wave: lane i holds h-word i
    const int vh = (int)hq[s & 1][lane];
    // 64 readlane -> SGPR, each feeding 2 sdot4 (rows of this thread)
    int a0 = 0, a1 = 0, b0 = 0, b1 = 0;
    #pragma unroll
    for (int j = 0; j < 64; j += 2) {
      const int h0w = __builtin_amdgcn_readlane(vh, j);
      const int h1w = __builtin_amdgcn_readlane(vh, j + 1);
      a0 = sdot4(w8[j],      (u32)h0w, a0);
      b0 = sdot4(w8[64 + j], (u32)h0w, b0);
      a1 = sdot4(w8[j + 1],      (u32)h1w, a1);
      b1 = sdot4(w8[64 + j + 1], (u32)h1w, b1);
    }
    const float x0 = (float)(a0 + a1) * fs0
                   + __half2float(__ushort_as_half((u16)(gx & 0xffff)));
    const float x1 = (float)(b0 + b1) * fs1
                   + __half2float(__ushort_as_half((u16)(gx >> 16)));
    gx = gn;
    float iv = 0.f, fv = 0.f;
    if (pp == 0) {          // gates i, f
      iv = sigm(x0);
      fv = sigm(x1);
    } else {                // gates g, o
      const float gv = tanh_fast(x0);
      const float ov = sigm(x1);
      xch[d] = make_float2(gv, ov);
    }
    __syncthreads();
    if (pp == 0) {
      const float2 go = xch[d];
      creg = __builtin_fmaf(fv, creg, iv * go.x);
      const float h = go.y * tanh_fast(creg);
      hist[(s & 127) * 256 + d] = __half_as_ushort(__float2half(h));
      int q = max(-127, min(127, (int)rintf(h * 32.f)));
      int q1 = __shfl_down(q, 1), q2 = __shfl_down(q, 2), q3 = __shfl_down(q, 3);
      if ((d & 3) == 0) hq[(s + 1) & 1][d >> 2] = packq(q, q1, q2, q3);
    }
    __syncthreads();
    if ((s & 127) == 127) {   // flush fp16 history -> out_lstm
      const int sbase = s - 127;
      #pragma unroll 4
      for (int i = 0; i < 16; ++i) {
        const int idx = t + i * 512;           // uint2 index into hist
        const int step = idx >> 6, d0 = (idx & 63) * 4;
        const int tt = sbase + step;
        const int tg = dir ? (T_LEN - 1 - tt) : tt;
        uint2 hv = ((const uint2*)hist)[idx];
        float4 ov4;
        ov4.x = __half2float(__ushort_as_half((u16)(hv.x & 0xffff)));
        ov4.y = __half2float(__ushort_as_half((u16)(hv.x >> 16)));
        ov4.z = __half2float(__ushort_as_half((u16)(hv.y & 0xffff)));
        ov4.w = __half2float(__ushort_as_half((u16)(hv.y >> 16)));
        *(float4*)&out_lstm[(size_t)tg * 512 + dir * 256 + d0] = ov4;
      }
      __syncthreads();
    }
  }
}

// ---------------------------------------------------------------------------
__global__ __launch_bounds__(256) void attn_kernel(
    const float* __restrict__ out_lstm, const float* __restrict__ w_omega,
    const float* __restrict__ u_omega, float* __restrict__ logits)
{
  __shared__ float bst[32][132];
  const int c0 = blockIdx.x * 32;
  const int t0 = blockIdx.y * 32;
  const int tid = threadIdx.x;
  const int ttb = tid >> 4, cgb = tid & 15;
  const float* a0p = out_lstm + (size_t)(t0 + ttb) * 512;
  const float* a1p = out_lstm + (size_t)(t0 + ttb + 16) * 512;
  float acc00 = 0, acc01 = 0, acc10 = 0, acc11 = 0;
  for (int kh = 0; kh < 4; ++kh) {
    __syncthreads();
    {
      const int cc = tid & 31;
      const int kA = tid >> 5;
      #pragma unroll
      for (int p = 0; p < 16; ++p) {
        const int kkx = kA + p * 8;
        bst[cc][kkx] = w_omega[(size_t)(kh * 128 + kkx) * 512 + c0 + cc];
      }
    }
    __syncthreads();
    #pragma unroll 4
    for (int k4 = 0; k4 < 128; k4 += 4) {
      float4 a0 = *(const float4*)(a0p + kh * 128 + k4);
      float4 a1 = *(const float4*)(a1p + kh * 128 + k4);
      float4 b0 = *(const float4*)&bst[cgb][k4];
      float4 b1 = *(const float4*)&bst[cgb + 16][k4];
      acc00 += a0.x*b0.x + a0.y*b0.y + a0.z*b0.z + a0.w*b0.w;
      acc01 += a0.x*b1.x + a0.y*b1.y + a0.z*b1.z + a0.w*b1.w;
      acc10 += a1.x*b0.x + a1.y*b0.y + a1.z*b0.z + a1.w*b0.w;
      acc11 += a1.x*b1.x + a1.y*b1.y + a1.z*b1.z + a1.w*b1.w;
    }
  }
  const float u0 = u_omega[c0 + cgb], u1 = u_omega[c0 + 16 + cgb];
  float s0 = tanh_fast(acc00) * u0 + tanh_fast(acc01) * u1;
  float s1 = tanh_fast(acc10) * u0 + tanh_fast(acc11) * u1;
  #pragma unroll
  for (int msk = 1; msk < 16; msk <<= 1) {
    s0 += __shfl_xor(s0, msk);
    s1 += __shfl_xor(s1, msk);
  }
  if (cgb == 0) {
    atomicAdd(&logits[t0 + ttb], s0);
    atomicAdd(&logits[t0 + ttb + 16], s1);
  }
}

// ---------------------------------------------------------------------------
__global__ __launch_bounds__(1024) void softmax_kernel(
    const float* __restrict__ logits, float* __restrict__ alphas)
{
  __shared__ float red[1024];
  const int tid = threadIdx.x;
  float l0 = logits[tid], l1 = logits[1024 + tid];
  float l2 = logits[2048 + tid], l3 = logits[3072 + tid];
  red[tid] = fmaxf(fmaxf(l0, l1), fmaxf(l2, l3));
  __syncthreads();
  for (int s = 512; s > 0; s >>= 1) {
    if (tid < s) red[tid] = fmaxf(red[tid], red[tid + s]);
    __syncthreads();
  }
  const float gm = red[0];
  __syncthreads();
  float e0 = __expf(l0 - gm), e1 = __expf(l1 - gm);
  float e2 = __expf(l2 - gm), e3 = __expf(l3 - gm);
  red[tid] = e0 + e1 + e2 + e3;
  __syncthreads();
  for (int s = 512; s > 0; s >>= 1) {
    if (tid < s) red[tid] += red[tid + s];
    __syncthreads();
  }
  const float inv = 1.0f / red[0];
  alphas[tid] = e0 * inv; alphas[1024 + tid] = e1 * inv;
  alphas[2048 + tid] = e2 * inv; alphas[3072 + tid] = e3 * inv;
}

// ---------------------------------------------------------------------------
__global__ __launch_bounds__(256) void feats_kernel(
    const float* __restrict__ out_lstm, const float* __restrict__ W_tag,
    const float* __restrict__ b_tag, const float* __restrict__ alphas,
    float* __restrict__ feats)
{
  __shared__ float wt[16][516];
  const int t0 = blockIdx.x * 16;
  const int tid = threadIdx.x;
  {
    const int k4 = (tid & 127) * 4;
    const int gA = tid >> 7;
    #pragma unroll
    for (int p = 0; p < 8; ++p) {
      const int tg = gA + p * 2;
      *(float4*)&wt[tg][k4] = *(const float4*)(W_tag + (size_t)tg * 512 + k4);
    }
  }
  __syncthreads();
  const int tt = tid >> 4, tg = tid & 15;
  const float* ap = out_lstm + (size_t)(t0 + tt) * 512;
  float acc = 0.f;
  #pragma unroll 4
  for (int k4 = 0; k4 < 512; k4 += 4) {
    float4 a = *(const float4*)(ap + k4);
    float4 b = *(const float4*)&wt[tg][k4];
    acc += a.x*b.x + a.y*b.y + a.z*b.z + a.w*b.w;
  }
  feats[(size_t)(t0 + tt) * 16 + tg] = acc * alphas[t0 + tt] + b_tag[tg];
}

// ---------------------------------------------------------------------------
__global__ __launch_bounds__(256) void vit_block_mats(
    const float* __restrict__ feats, const float* __restrict__ trans,
    float* __restrict__ Cmat)
{
  __shared__ float C[2][16][17];
  const int b = blockIdx.x;
  const int tid = threadIdx.x;
  const int n = tid >> 4, p = tid & 15;
  float tr[16];
  #pragma unroll
  for (int k = 0; k < 16; ++k) tr[k] = trans[n * 16 + k];
  const int t0 = b * 32;
  C[0][n][p] = tr[p] + feats[t0 * 16 + n];
  float fnext = feats[(t0 + 1) * 16 + n];
  __syncthreads();
  for (int s = 1; s < 32; ++s) {
    const float ft = fnext;
    if (s + 1 < 32) fnext = feats[(t0 + s + 1) * 16 + n];
    const int pr = (s - 1) & 1, cu = s & 1;
    float m = tr[0] + C[pr][0][p];
    #pragma unroll
    for (int k = 1; k < 16; ++k) m = fmaxf(m, tr[k] + C[pr][k][p]);
    C[cu][n][p] = m + ft;
    __syncthreads();
  }
  Cmat[b * 256 + n * 16 + p] = C[1][n][p];
}

__global__ __launch_bounds__(64) void vit_scan(
    const float* __restrict__ Cmat, const float* __restrict__ trans,
    float* __restrict__ v_in, float* __restrict__ d_out, u32* __restrict__ best_ws)
{
  const int l = threadIdx.x;
  const int n = l & 15, pg = l >> 4;
  float v = (n == START_TAG) ? 0.f : NEG_VAL;
  for (int b = 0; b < 128; ++b) {
    if (pg == 0) v_in[b * 16 + n] = v;
    float4 c4 = *(const float4*)&Cmat[b * 256 + n * 16 + pg * 4];
    float cand = c4.x + __shfl(v, pg * 4 + 0);
    cand = fmaxf(cand, c4.y + __shfl(v, pg * 4 + 1));
    cand = fmaxf(cand, c4.z + __shfl(v, pg * 4 + 2));
    cand = fmaxf(cand, c4.w + __shfl(v, pg * 4 + 3));
    cand = fmaxf(cand, __shfl_xor(cand, 16));
    cand = fmaxf(cand, __shfl_xor(cand, 32));
    v = cand;
  }
  float term = v + trans[STOP_TAG * 16 + n];
  int mi = n;
  #pragma unroll
  for (int msk = 1; msk < 16; msk <<= 1) {
    float om = __shfl_xor(term, msk); int omi = __shfl_xor(mi, msk);
    if (om > term || (om == term && omi < mi)) { term = om; mi = omi; }
  }
  if (l == 0) { d_out[0] = term; *best_ws = (u32)mi; }
}

__global__ __launch_bounds__(64) void vit_bp(
    const float* __restrict__ feats, const float* __restrict__ trans,
    const float* __restrict__ v_in, u32* __restrict__ bp)
{
  const int b = blockIdx.x;
  const int l = threadIdx.x;
  const int n = l & 15, pg = l >> 4;
  const float4 tr4 = *(const float4*)&trans[n * 16 + pg * 4];
  float v = v_in[b * 16 + n];
  const int t0 = b * 32;
  float fcur = feats[t0 * 16 + n];
  for (int s = 0; s < 32; ++s) {
    const int t = t0 + s;
    float fnext = (s + 1 < 32) ? feats[(t + 1) * 16 + n] : 0.f;
    float f0 = __shfl(v, pg * 4 + 0), f1 = __shfl(v, pg * 4 + 1);
    float f2 = __shfl(v, pg * 4 + 2), f3 = __shfl(v, pg * 4 + 3);
    float m = f0 + tr4.x; int mi = pg * 4;
    float c;
    c = f1 + tr4.y; if (c > m) { m = c; mi = pg * 4 + 1; }
    c = f2 + tr4.z; if (c > m) { m = c; mi = pg * 4 + 2; }
    c = f3 + tr4.w; if (c > m) { m = c; mi = pg * 4 + 3; }
    float om; int omi;
    om = __shfl_xor(m, 16); omi = __shfl_xor(mi, 16);
    if (om > m || (om == m && omi < mi)) { m = om; mi = omi; }
    om = __shfl_xor(m, 32); omi = __shfl_xor(mi, 32);
    if (om > m || (om == m && omi < mi)) { m = om; mi = omi; }
    u32 w = (l < 16) ? ((u32)mi << ((n & 7) * 4)) : 0u;
    w |= __shfl_xor(w, 1); w |= __shfl_xor(w, 2); w |= __shfl_xor(w, 4);
    if (l == 0) bp[t * 2] = w;
    if (l == 8) bp[t * 2 + 1] = w;
    v = m + fcur;
    fcur = fnext;
  }
}

__global__ __launch_bounds__(64) void vit_bmap(
    const u32* __restrict__ bp, u32* __restrict__ Bmap)
{
  const int b = blockIdx.x;
  const int l = threadIdx.x;
  if (l >= 16) return;
  int t = b * 32 + 31;
  u32 lo = bp[t * 2], hi = bp[t * 2 + 1];
  int A = (int)(((l < 8 ? lo : hi) >> ((l & 7) * 4)) & 15u);
  for (t = b * 32 + 30; t >= b * 32; --t) {
    lo = bp[t * 2]; hi = bp[t * 2 + 1];
    A = (int)(((A < 8 ? lo : hi) >> ((A & 7) * 4)) & 15u);
  }
  Bmap[b * 16 + l] = (u32)A;
}

__global__ __launch_bounds__(64) void vit_suffix(
    const u32* __restrict__ Bmap, u32* __restrict__ Stail)
{
  __shared__ u32 bm[2048];
  const int l = threadIdx.x;
  for (int i = l; i < 2048; i += 64) bm[i] = Bmap[i];
  __syncthreads();
  if (l < 16) {
    int S = l;
    for (int b = 127; b >= 0; --b) {
      Stail[b * 16 + l] = (u32)S;
      S = (int)bm[b * 16 + S];
    }
  }
}

__global__ __launch_bounds__(64) void vit_emit(
    const u32* __restrict__ bp, const u32* __restrict__ Stail,
    const u32* __restrict__ best_ws, float* __restrict__ d_out)
{
  const int b = blockIdx.x;
  const int l = threadIdx.x;
  const int best = (int)*best_ws;
  int A = (l < 16) ? (int)Stail[b * 16 + l] : 0;
  for (int s = 31; s >= 0; --s) {
    const int t = b * 32 + s;
    const int pv = __shfl(A, best);
    if (l == 0) d_out[1 + t] = (float)pv;
    if (s > 0) {
      const u32 lo = bp[t * 2], hi = bp[t * 2 + 1];
      A = (int)(((A < 8 ? lo : hi) >> ((A & 7) * 4)) & 15u);
    }
  }
}

// ---------------------------------------------------------------------------
extern "C" void kernel_launch(void* const* d_in, const int* in_sizes, int n_in,
                              void* d_out, int out_size, void* d_ws, size_t ws_size,
                              hipStream_t stream)
{
  const int*   sentence = (const int*)  d_in[0];
  const float* emb      = (const float*)d_in[1];
  const float* Wih_f    = (const float*)d_in[2];
  const float* Whh_f    = (const float*)d_in[3];
  const float* bih_f    = (const float*)d_in[4];
  const float* bhh_f    = (const float*)d_in[5];
  const float* Wih_b    = (const float*)d_in[6];
  const float* Whh_b    = (const float*)d_in[7];
  const float* bih_b    = (const float*)d_in[8];
  const float* bhh_b    = (const float*)d_in[9];
  const float* h0       = (const float*)d_in[10];
  const float* c0       = (const float*)d_in[11];
  const float* w_omega  = (const float*)d_in[12];
  const float* u_omega  = (const float*)d_in[13];
  const float* W_tag    = (const float*)d_in[14];
  const float* b_tag    = (const float*)d_in[15];
  const float* trans    = (const float*)d_in[16];

  char* ws = (char*)d_ws;
  __half* Gx      = (__half*)(ws + GX_OFF);
  float* out_lstm = (float*)(ws + OUT_OFF);
  float* logits   = (float*)(ws + LOGITS_OFF);
  float* alphas   = (float*)(ws + ALPHAS_OFF);
  float* feats    = (float*)(ws + FEATS_OFF);
  float* Cmat     = (float*)(ws + CMAT_OFF);
  float* v_in     = (float*)(ws + VIN_OFF);
  u32*   bp       = (u32*)  (ws + BP_OFF);
  u32*   Bmap     = (u32*)  (ws + BMAP_OFF);
  u32*   Stail    = (u32*)  (ws + STAIL_OFF);
  u32*   best_ws  = (u32*)  (ws + BEST_OFF);
  float* out      = (float*)d_out;

  hipLaunchKernelGGL(prep_kernel, dim3(4), dim3(1024), 0, stream, logits);
  hipLaunchKernelGGL(gx_kernel, dim3(64, 128), dim3(256), 0, stream,
                     sentence, emb, Wih_f, Wih_b, bih_f, bhh_f, bih_b, bhh_b, Gx);
  hipLaunchKernelGGL(lstm_kernel, dim3(2), dim3(512), 0, stream,
                     Whh_f, Whh_b, h0, c0, Gx, out_lstm);
  hipLaunchKernelGGL(attn_kernel, dim3(16, 128), dim3(256), 0, stream,
                     out_lstm, w_omega, u_omega, logits);
  hipLaunchKernelGGL(softmax_kernel, dim3(1), dim3(1024), 0, stream, logits, alphas);
  hipLaunchKernelGGL(feats_kernel, dim3(256), dim3(256), 0, stream,
                     out_lstm, W_tag, b_tag, alphas, feats);
  hipLaunchKernelGGL(vit_block_mats, dim3(128), dim3(256), 0, stream,
                     feats, trans, Cmat);
  hipLaunchKernelGGL(vit_scan, dim3(1), dim3(64), 0, stream,
                     Cmat, trans, v_in, out, best_ws);
  hipLaunchKernelGGL(vit_bp, dim3(128), dim3(64), 0, stream,
                     feats, trans, v_in, bp);
  hipLaunchKernelGGL(vit_bmap, dim3(128), dim3(64), 0, stream, bp, Bmap);
  hipLaunchKernelGGL(vit_suffix, dim3(1), dim3(64), 0, stream, Bmap, Stail);
  hipLaunchKernelGGL(vit_emit, dim3(128), dim3(64), 0, stream,
                     bp, Stail, best_ws, out);
}

// Round 6
// 4069.683 us; speedup vs baseline: 1.5877x; 1.3354x over previous
//
#include <hip/hip_runtime.h>
#include <hip/hip_fp16.h>

#define T_LEN 4096
#define START_TAG 14
#define STOP_TAG 15
#define NEG_VAL -10000.0f

typedef unsigned int u32;
typedef unsigned short u16;
typedef unsigned long long u64;
typedef int v4i __attribute__((ext_vector_type(4)));

// ---------- ws layout (bytes) ----------
#define GX_OFF      0u              // __half [4096][2048]  (dir*1024 + d*4 + gate)
#define OUT_OFF     16777216u       // float  [4096][512]
#define LOGITS_OFF  25165824u       // float  [4096]
#define ALPHAS_OFF  25182208u       // float  [4096]
#define FEATS_OFF   25198592u       // float  [4096][16]
#define CMAT_OFF    25460736u       // float  [128][16][16]
#define VIN_OFF     25591808u       // float  [128][16]
#define BP_OFF      25600000u       // u32    [4096][2]
#define BMAP_OFF    25632768u       // u32    [128][16]
#define STAIL_OFF   25640960u       // u32    [128][16]
#define BEST_OFF    25649152u       // u32    [1]

__device__ __forceinline__ u32 packq(int q0, int q1, int q2, int q3) {
  return (u32)(q0 & 255) | ((u32)(q1 & 255) << 8) |
         ((u32)(q2 & 255) << 16) | ((u32)(q3 & 255) << 24);
}

__device__ __forceinline__ float sigm(float x) {
  return __builtin_amdgcn_rcpf(1.f + __expf(-x));
}
__device__ __forceinline__ float tanh_fast(float x) {
  float e = __expf(-2.f * fabsf(x));
  float r = (1.f - e) * __builtin_amdgcn_rcpf(1.f + e);
  return copysignf(r, x);
}

// ---------------------------------------------------------------------------
__global__ void prep_kernel(float* logits) {
  const int i = threadIdx.x + blockIdx.x * 1024;
  if (i < 4096) logits[i] = 0.f;
}

// ---------------------------------------------------------------------------
// Gx[t][dir*1024 + d*4 + gate] = emb[sentence[t]] . W-row + bih + bhh
__global__ __launch_bounds__(256) void gx_kernel(
    const int* __restrict__ sentence, const float* __restrict__ emb,
    const float* __restrict__ Wih_f, const float* __restrict__ Wih_b,
    const float* __restrict__ bih_f, const float* __restrict__ bhh_f,
    const float* __restrict__ bih_b, const float* __restrict__ bhh_b,
    __half* __restrict__ Gx)
{
  __shared__ float ws[32][260];
  const int r0 = blockIdx.x * 32;
  const int t0 = blockIdx.y * 32;
  const int tid = threadIdx.x;
  {
    const int c4 = (tid & 63) * 4;
    const int rA = tid >> 6;
    #pragma unroll
    for (int p = 0; p < 8; ++p) {
      const int rr = rA + p * 4;
      const int R = r0 + rr;
      const float* src = (R < 1024) ? (Wih_f + (size_t)R * 256 + c4)
                                    : (Wih_b + (size_t)(R - 1024) * 256 + c4);
      *(float4*)&ws[rr][c4] = *(const float4*)src;
    }
  }
  __syncthreads();
  const int ttb = tid >> 4, rgb = tid & 15;
  const int s0r = sentence[t0 + ttb];
  const int s1r = sentence[t0 + ttb + 16];
  const float* x0p = emb + (size_t)s0r * 256;
  const float* x1p = emb + (size_t)s1r * 256;
  float acc00 = 0, acc01 = 0, acc10 = 0, acc11 = 0;
  #pragma unroll 4
  for (int c4 = 0; c4 < 256; c4 += 4) {
    float4 x0 = *(const float4*)(x0p + c4);
    float4 x1 = *(const float4*)(x1p + c4);
    float4 w0 = *(const float4*)&ws[rgb][c4];
    float4 w1 = *(const float4*)&ws[rgb + 16][c4];
    acc00 += x0.x*w0.x + x0.y*w0.y + x0.z*w0.z + x0.w*w0.w;
    acc01 += x0.x*w1.x + x0.y*w1.y + x0.z*w1.z + x0.w*w1.w;
    acc10 += x1.x*w0.x + x1.y*w0.y + x1.z*w0.z + x1.w*w0.w;
    acc11 += x1.x*w1.x + x1.y*w1.y + x1.z*w1.z + x1.w*w1.w;
  }
  #pragma unroll
  for (int ri = 0; ri < 2; ++ri) {
    const int R = r0 + rgb + ri * 16;
    const int dir = R >> 10, grow = R & 1023;
    const int gate = grow >> 8, dd = grow & 255;
    const float bias = dir ? (bih_b[grow] + bhh_b[grow])
                           : (bih_f[grow] + bhh_f[grow]);
    const float a0 = ri ? acc01 : acc00;
    const float a1 = ri ? acc11 : acc10;
    const size_t off = (size_t)dir * 1024 + dd * 4 + gate;
    Gx[(size_t)(t0 + ttb) * 2048 + off]      = __float2half(a0 + bias);
    Gx[(size_t)(t0 + ttb + 16) * 2048 + off] = __float2half(a1 + bias);
  }
}

// ---------------------------------------------------------------------------
// Recurrence v6: grid=2 (dir), 512 threads (8 waves). The 1024x256 matvec
// runs on the MFMA pipe: v_mfma_i32_16x16x64_i8, weights as A-fragments in
// VGPRs (per-row int8 quant), h as B-fragment col 0 (cols 1-15 garbage,
// harmless: C is column-separable). Wave w owns rows 128w..128w+127
// (8 M-tiles x 4 K-tiles = 32 MFMA/step). C col 0 lives in lanes with
// (lane&15)==0: rows quad*4+reg -> masked ds_write_b128 to graw.
// Activation: 256 threads, thread-local i,f,g,o. Gx batched 16 steps into
// registers so the vmcnt(0) barrier drain is paid once per 16 steps.
__global__ __launch_bounds__(512, 2) void lstm_kernel(
    const float* __restrict__ Whh_f, const float* __restrict__ Whh_b,
    const float* __restrict__ h0, const float* __restrict__ c0,
    const __half* __restrict__ Gx, float* __restrict__ out_lstm)
{
  const int dir = blockIdx.x;
  const int tid = threadIdx.x;
  const int w = tid >> 6, l = tid & 63;
  const int mr = l & 15, q = l >> 4;
  const float* Whh = dir ? Whh_b : Whh_f;

  __shared__ __align__(16) char hq8[2][256];    // int8 h, parity buffers
  __shared__ __align__(16) int graw[1024];      // raw i32 gate sums
  __shared__ float fsh[1024];                   // per-row scales (init only)
  __shared__ __align__(16) u16 hist[128 * 256]; // 64 KB fp16 h history

  // ---- init: load + quantize weights into A-fragments ----
  // lane holds A[row=128w+16m+mr][k=64t+16q+j], j=0..15 bytes (LE in v4i)
  v4i wfrag[8][4];
  #pragma unroll
  for (int m = 0; m < 8; ++m) {
    const int row = 128 * w + 16 * m + mr;
    const float* wr = Whh + (size_t)row * 256 + 16 * q;
    float mx = 1e-10f;
    #pragma unroll
    for (int t = 0; t < 4; ++t) {
      #pragma unroll
      for (int c4 = 0; c4 < 4; ++c4) {
        float4 f = *(const float4*)(wr + 64 * t + 4 * c4);
        mx = fmaxf(mx, fmaxf(fmaxf(fabsf(f.x), fabsf(f.y)),
                             fmaxf(fabsf(f.z), fabsf(f.w))));
      }
    }
    mx = fmaxf(mx, __shfl_xor(mx, 16));
    mx = fmaxf(mx, __shfl_xor(mx, 32));
    const float qs = 127.f / mx;
    if (q == 0) fsh[row] = mx * (1.f / (127.f * 32.f));  // w-scale * h-scale
    #pragma unroll
    for (int t = 0; t < 4; ++t) {
      u32 pk[4];
      #pragma unroll
      for (int c4 = 0; c4 < 4; ++c4) {
        float4 f = *(const float4*)(wr + 64 * t + 4 * c4);
        pk[c4] = packq((int)rintf(f.x * qs), (int)rintf(f.y * qs),
                       (int)rintf(f.z * qs), (int)rintf(f.w * qs));
      }
      v4i v; v[0] = (int)pk[0]; v[1] = (int)pk[1]; v[2] = (int)pk[2]; v[3] = (int)pk[3];
      wfrag[m][t] = v;
    }
  }

  float creg = 0.f;
  if (tid < 256) {
    creg = c0[dir * 256 + tid];
    float hv = h0[dir * 256 + tid];
    int qq = max(-127, min(127, (int)rintf(hv * 32.f)));
    hq8[0][tid] = (char)qq;
  }
  __syncthreads();

  // per-thread gate scales for the activation phase
  float fsi = 0.f, fsf = 0.f, fsg = 0.f, fso = 0.f;
  if (tid < 256) {
    fsi = fsh[tid]; fsf = fsh[256 + tid];
    fsg = fsh[512 + tid]; fso = fsh[768 + tid];
  }
  const uint2* Gx2 = (const uint2*)Gx;

  for (int sb = 0; sb < T_LEN; sb += 16) {
    uint2 gb[16];
    if (tid < 256) {
      #pragma unroll
      for (int k = 0; k < 16; ++k) {
        const int t = dir ? (T_LEN - 1 - (sb + k)) : (sb + k);
        gb[k] = Gx2[(size_t)t * 512 + dir * 256 + tid];
      }
    }
    #pragma unroll
    for (int k = 0; k < 16; ++k) {
      const int s = sb + k;
      // ---- MFMA phase ----
      const char* hc = hq8[k & 1];
      v4i bfr[4];
      #pragma unroll
      for (int t = 0; t < 4; ++t)
        bfr[t] = *(const v4i*)(hc + 64 * t + 16 * q);
      #pragma unroll
      for (int m = 0; m < 8; ++m) {
        v4i acc; acc[0] = 0; acc[1] = 0; acc[2] = 0; acc[3] = 0;
        acc = __builtin_amdgcn_mfma_i32_16x16x64_i8(wfrag[m][0], bfr[0], acc, 0, 0, 0);
        acc = __builtin_amdgcn_mfma_i32_16x16x64_i8(wfrag[m][1], bfr[1], acc, 0, 0, 0);
        acc = __builtin_amdgcn_mfma_i32_16x16x64_i8(wfrag[m][2], bfr[2], acc, 0, 0, 0);
        acc = __builtin_amdgcn_mfma_i32_16x16x64_i8(wfrag[m][3], bfr[3], acc, 0, 0, 0);
        if (mr == 0)   // col 0 of C: rows 128w+16m+4q+{0..3} in regs 0..3
          *(v4i*)&graw[128 * w + 16 * m + 4 * q] = acc;
      }
      __syncthreads();
      // ---- activation phase (256 threads, thread-local gates) ----
      if (tid < 256) {
        const int d = tid;
        const int ri = graw[d],        rf = graw[256 + d];
        const int rg = graw[512 + d],  ro = graw[768 + d];
        const float xi = (float)ri * fsi + __half2float(__ushort_as_half((u16)(gb[k].x & 0xffff)));
        const float xf = (float)rf * fsf + __half2float(__ushort_as_half((u16)(gb[k].x >> 16)));
        const float xg = (float)rg * fsg + __half2float(__ushort_as_half((u16)(gb[k].y & 0xffff)));
        const float xo = (float)ro * fso + __half2float(__ushort_as_half((u16)(gb[k].y >> 16)));
        const float iv = sigm(xi);
        const float fv = sigm(xf);
        const float gv = tanh_fast(xg);
        const float ov = sigm(xo);
        creg = __builtin_fmaf(fv, creg, iv * gv);
        const float h = ov * tanh_fast(creg);
        hist[(s & 127) * 256 + d] = __half_as_ushort(__float2half(h));
        int qq = max(-127, min(127, (int)rintf(h * 32.f)));
        hq8[(k + 1) & 1][d] = (char)qq;
      }
      __syncthreads();
      if ((s & 127) == 127) {   // flush fp16 history -> out_lstm
        const int sbase = s - 127;
        #pragma unroll 4
        for (int i = 0; i < 16; ++i) {
          const int idx = tid + i * 512;         // uint2 index into hist
          const int step = idx >> 6, d0 = (idx & 63) * 4;
          const int tt = sbase + step;
          const int tg = dir ? (T_LEN - 1 - tt) : tt;
          uint2 hv = ((const uint2*)hist)[idx];
          float4 ov4;
          ov4.x = __half2float(__ushort_as_half((u16)(hv.x & 0xffff)));
          ov4.y = __half2float(__ushort_as_half((u16)(hv.x >> 16)));
          ov4.z = __half2float(__ushort_as_half((u16)(hv.y & 0xffff)));
          ov4.w = __half2float(__ushort_as_half((u16)(hv.y >> 16)));
          *(float4*)&out_lstm[(size_t)tg * 512 + dir * 256 + d0] = ov4;
        }
        __syncthreads();
      }
    }
  }
}

// ---------------------------------------------------------------------------
__global__ __launch_bounds__(256) void attn_kernel(
    const float* __restrict__ out_lstm, const float* __restrict__ w_omega,
    const float* __restrict__ u_omega, float* __restrict__ logits)
{
  __shared__ float bst[32][132];
  const int c0 = blockIdx.x * 32;
  const int t0 = blockIdx.y * 32;
  const int tid = threadIdx.x;
  const int ttb = tid >> 4, cgb = tid & 15;
  const float* a0p = out_lstm + (size_t)(t0 + ttb) * 512;
  const float* a1p = out_lstm + (size_t)(t0 + ttb + 16) * 512;
  float acc00 = 0, acc01 = 0, acc10 = 0, acc11 = 0;
  for (int kh = 0; kh < 4; ++kh) {
    __syncthreads();
    {
      const int cc = tid & 31;
      const int kA = tid >> 5;
      #pragma unroll
      for (int p = 0; p < 16; ++p) {
        const int kkx = kA + p * 8;
        bst[cc][kkx] = w_omega[(size_t)(kh * 128 + kkx) * 512 + c0 + cc];
      }
    }
    __syncthreads();
    #pragma unroll 4
    for (int k4 = 0; k4 < 128; k4 += 4) {
      float4 a0 = *(const float4*)(a0p + kh * 128 + k4);
      float4 a1 = *(const float4*)(a1p + kh * 128 + k4);
      float4 b0 = *(const float4*)&bst[cgb][k4];
      float4 b1 = *(const float4*)&bst[cgb + 16][k4];
      acc00 += a0.x*b0.x + a0.y*b0.y + a0.z*b0.z + a0.w*b0.w;
      acc01 += a0.x*b1.x + a0.y*b1.y + a0.z*b1.z + a0.w*b1.w;
      acc10 += a1.x*b0.x + a1.y*b0.y + a1.z*b0.z + a1.w*b0.w;
      acc11 += a1.x*b1.x + a1.y*b1.y + a1.z*b1.z + a1.w*b1.w;
    }
  }
  const float u0 = u_omega[c0 + cgb], u1 = u_omega[c0 + 16 + cgb];
  float s0 = tanh_fast(acc00) * u0 + tanh_fast(acc01) * u1;
  float s1 = tanh_fast(acc10) * u0 + tanh_fast(acc11) * u1;
  #pragma unroll
  for (int msk = 1; msk < 16; msk <<= 1) {
    s0 += __shfl_xor(s0, msk);
    s1 += __shfl_xor(s1, msk);
  }
  if (cgb == 0) {
    atomicAdd(&logits[t0 + ttb], s0);
    atomicAdd(&logits[t0 + ttb + 16], s1);
  }
}

// ---------------------------------------------------------------------------
__global__ __launch_bounds__(1024) void softmax_kernel(
    const float* __restrict__ logits, float* __restrict__ alphas)
{
  __shared__ float red[1024];
  const int tid = threadIdx.x;
  float l0 = logits[tid], l1 = logits[1024 + tid];
  float l2 = logits[2048 + tid], l3 = logits[3072 + tid];
  red[tid] = fmaxf(fmaxf(l0, l1), fmaxf(l2, l3));
  __syncthreads();
  for (int s = 512; s > 0; s >>= 1) {
    if (tid < s) red[tid] = fmaxf(red[tid], red[tid + s]);
    __syncthreads();
  }
  const float gm = red[0];
  __syncthreads();
  float e0 = __expf(l0 - gm), e1 = __expf(l1 - gm);
  float e2 = __expf(l2 - gm), e3 = __expf(l3 - gm);
  red[tid] = e0 + e1 + e2 + e3;
  __syncthreads();
  for (int s = 512; s > 0; s >>= 1) {
    if (tid < s) red[tid] += red[tid + s];
    __syncthreads();
  }
  const float inv = 1.0f / red[0];
  alphas[tid] = e0 * inv; alphas[1024 + tid] = e1 * inv;
  alphas[2048 + tid] = e2 * inv; alphas[3072 + tid] = e3 * inv;
}

// ---------------------------------------------------------------------------
__global__ __launch_bounds__(256) void feats_kernel(
    const float* __restrict__ out_lstm, const float* __restrict__ W_tag,
    const float* __restrict__ b_tag, const float* __restrict__ alphas,
    float* __restrict__ feats)
{
  __shared__ float wt[16][516];
  const int t0 = blockIdx.x * 16;
  const int tid = threadIdx.x;
  {
    const int k4 = (tid & 127) * 4;
    const int gA = tid >> 7;
    #pragma unroll
    for (int p = 0; p < 8; ++p) {
      const int tg = gA + p * 2;
      *(float4*)&wt[tg][k4] = *(const float4*)(W_tag + (size_t)tg * 512 + k4);
    }
  }
  __syncthreads();
  const int tt = tid >> 4, tg = tid & 15;
  const float* ap = out_lstm + (size_t)(t0 + tt) * 512;
  float acc = 0.f;
  #pragma unroll 4
  for (int k4 = 0; k4 < 512; k4 += 4) {
    float4 a = *(const float4*)(ap + k4);
    float4 b = *(const float4*)&wt[tg][k4];
    acc += a.x*b.x + a.y*b.y + a.z*b.z + a.w*b.w;
  }
  feats[(size_t)(t0 + tt) * 16 + tg] = acc * alphas[t0 + tt] + b_tag[tg];
}

// ---------------------------------------------------------------------------
__global__ __launch_bounds__(256) void vit_block_mats(
    const float* __restrict__ feats, const float* __restrict__ trans,
    float* __restrict__ Cmat)
{
  __shared__ float C[2][16][17];
  const int b = blockIdx.x;
  const int tid = threadIdx.x;
  const int n = tid >> 4, p = tid & 15;
  float tr[16];
  #pragma unroll
  for (int k = 0; k < 16; ++k) tr[k] = trans[n * 16 + k];
  const int t0 = b * 32;
  C[0][n][p] = tr[p] + feats[t0 * 16 + n];
  float fnext = feats[(t0 + 1) * 16 + n];
  __syncthreads();
  for (int s = 1; s < 32; ++s) {
    const float ft = fnext;
    if (s + 1 < 32) fnext = feats[(t0 + s + 1) * 16 + n];
    const int pr = (s - 1) & 1, cu = s & 1;
    float m = tr[0] + C[pr][0][p];
    #pragma unroll
    for (int k = 1; k < 16; ++k) m = fmaxf(m, tr[k] + C[pr][k][p]);
    C[cu][n][p] = m + ft;
    __syncthreads();
  }
  Cmat[b * 256 + n * 16 + p] = C[1][n][p];
}

__global__ __launch_bounds__(64) void vit_scan(
    const float* __restrict__ Cmat, const float* __restrict__ trans,
    float* __restrict__ v_in, float* __restrict__ d_out, u32* __restrict__ best_ws)
{
  const int l = threadIdx.x;
  const int n = l & 15, pg = l >> 4;
  float v = (n == START_TAG) ? 0.f : NEG_VAL;
  for (int b = 0; b < 128; ++b) {
    if (pg == 0) v_in[b * 16 + n] = v;
    float4 c4 = *(const float4*)&Cmat[b * 256 + n * 16 + pg * 4];
    float cand = c4.x + __shfl(v, pg * 4 + 0);
    cand = fmaxf(cand, c4.y + __shfl(v, pg * 4 + 1));
    cand = fmaxf(cand, c4.z + __shfl(v, pg * 4 + 2));
    cand = fmaxf(cand, c4.w + __shfl(v, pg * 4 + 3));
    cand = fmaxf(cand, __shfl_xor(cand, 16));
    cand = fmaxf(cand, __shfl_xor(cand, 32));
    v = cand;
  }
  float term = v + trans[STOP_TAG * 16 + n];
  int mi = n;
  #pragma unroll
  for (int msk = 1; msk < 16; msk <<= 1) {
    float om = __shfl_xor(term, msk); int omi = __shfl_xor(mi, msk);
    if (om > term || (om == term && omi < mi)) { term = om; mi = omi; }
  }
  if (l == 0) { d_out[0] = term; *best_ws = (u32)mi; }
}

__global__ __launch_bounds__(64) void vit_bp(
    const float* __restrict__ feats, const float* __restrict__ trans,
    const float* __restrict__ v_in, u32* __restrict__ bp)
{
  const int b = blockIdx.x;
  const int l = threadIdx.x;
  const int n = l & 15, pg = l >> 4;
  const float4 tr4 = *(const float4*)&trans[n * 16 + pg * 4];
  float v = v_in[b * 16 + n];
  const int t0 = b * 32;
  float fcur = feats[t0 * 16 + n];
  for (int s = 0; s < 32; ++s) {
    const int t = t0 + s;
    float fnext = (s + 1 < 32) ? feats[(t + 1) * 16 + n] : 0.f;
    float f0 = __shfl(v, pg * 4 + 0), f1 = __shfl(v, pg * 4 + 1);
    float f2 = __shfl(v, pg * 4 + 2), f3 = __shfl(v, pg * 4 + 3);
    float m = f0 + tr4.x; int mi = pg * 4;
    float c;
    c = f1 + tr4.y; if (c > m) { m = c; mi = pg * 4 + 1; }
    c = f2 + tr4.z; if (c > m) { m = c; mi = pg * 4 + 2; }
    c = f3 + tr4.w; if (c > m) { m = c; mi = pg * 4 + 3; }
    float om; int omi;
    om = __shfl_xor(m, 16); omi = __shfl_xor(mi, 16);
    if (om > m || (om == m && omi < mi)) { m = om; mi = omi; }
    om = __shfl_xor(m, 32); omi = __shfl_xor(mi, 32);
    if (om > m || (om == m && omi < mi)) { m = om; mi = omi; }
    u32 w = (l < 16) ? ((u32)mi << ((n & 7) * 4)) : 0u;
    w |= __shfl_xor(w, 1); w |= __shfl_xor(w, 2); w |= __shfl_xor(w, 4);
    if (l == 0) bp[t * 2] = w;
    if (l == 8) bp[t * 2 + 1] = w;
    v = m + fcur;
    fcur = fnext;
  }
}

__global__ __launch_bounds__(64) void vit_bmap(
    const u32* __restrict__ bp, u32* __restrict__ Bmap)
{
  const int b = blockIdx.x;
  const int l = threadIdx.x;
  if (l >= 16) return;
  int t = b * 32 + 31;
  u32 lo = bp[t * 2], hi = bp[t * 2 + 1];
  int A = (int)(((l < 8 ? lo : hi) >> ((l & 7) * 4)) & 15u);
  for (t = b * 32 + 30; t >= b * 32; --t) {
    lo = bp[t * 2]; hi = bp[t * 2 + 1];
    A = (int)(((A < 8 ? lo : hi) >> ((A & 7) * 4)) & 15u);
  }
  Bmap[b * 16 + l] = (u32)A;
}

__global__ __launch_bounds__(64) void vit_suffix(
    const u32* __restrict__ Bmap, u32* __restrict__ Stail)
{
  __shared__ u32 bm[2048];
  const int l = threadIdx.x;
  for (int i = l; i < 2048; i += 64) bm[i] = Bmap[i];
  __syncthreads();
  if (l < 16) {
    int S = l;
    for (int b = 127; b >= 0; --b) {
      Stail[b * 16 + l] = (u32)S;
      S = (int)bm[b * 16 + S];
    }
  }
}

__global__ __launch_bounds__(64) void vit_emit(
    const u32* __restrict__ bp, const u32* __restrict__ Stail,
    const u32* __restrict__ best_ws, float* __restrict__ d_out)
{
  const int b = blockIdx.x;
  const int l = threadIdx.x;
  const int best = (int)*best_ws;
  int A = (l < 16) ? (int)Stail[b * 16 + l] : 0;
  for (int s = 31; s >= 0; --s) {
    const int t = b * 32 + s;
    const int pv = __shfl(A, best);
    if (l == 0) d_out[1 + t] = (float)pv;
    if (s > 0) {
      const u32 lo = bp[t * 2], hi = bp[t * 2 + 1];
      A = (int)(((A < 8 ? lo : hi) >> ((A & 7) * 4)) & 15u);
    }
  }
}

// ---------------------------------------------------------------------------
extern "C" void kernel_launch(void* const* d_in, const int* in_sizes, int n_in,
                              void* d_out, int out_size, void* d_ws, size_t ws_size,
                              hipStream_t stream)
{
  const int*   sentence = (const int*)  d_in[0];
  const float* emb      = (const float*)d_in[1];
  const float* Wih_f    = (const float*)d_in[2];
  const float* Whh_f    = (const float*)d_in[3];
  const float* bih_f    = (const float*)d_in[4];
  const float* bhh_f    = (const float*)d_in[5];
  const float* Wih_b    = (const float*)d_in[6];
  const float* Whh_b    = (const float*)d_in[7];
  const float* bih_b    = (const float*)d_in[8];
  const float* bhh_b    = (const float*)d_in[9];
  const float* h0       = (const float*)d_in[10];
  const float* c0       = (const float*)d_in[11];
  const float* w_omega  = (const float*)d_in[12];
  const float* u_omega  = (const float*)d_in[13];
  const float* W_tag    = (const float*)d_in[14];
  const float* b_tag    = (const float*)d_in[15];
  const float* trans    = (const float*)d_in[16];

  char* ws = (char*)d_ws;
  __half* Gx      = (__half*)(ws + GX_OFF);
  float* out_lstm = (float*)(ws + OUT_OFF);
  float* logits   = (float*)(ws + LOGITS_OFF);
  float* alphas   = (float*)(ws + ALPHAS_OFF);
  float* feats    = (float*)(ws + FEATS_OFF);
  float* Cmat     = (float*)(ws + CMAT_OFF);
  float* v_in     = (float*)(ws + VIN_OFF);
  u32*   bp       = (u32*)  (ws + BP_OFF);
  u32*   Bmap     = (u32*)  (ws + BMAP_OFF);
  u32*   Stail    = (u32*)  (ws + STAIL_OFF);
  u32*   best_ws  = (u32*)  (ws + BEST_OFF);
  float* out      = (float*)d_out;

  hipLaunchKernelGGL(prep_kernel, dim3(4), dim3(1024), 0, stream, logits);
  hipLaunchKernelGGL(gx_kernel, dim3(64, 128), dim3(256), 0, stream,
                     sentence, emb, Wih_f, Wih_b, bih_f, bhh_f, bih_b, bhh_b, Gx);
  hipLaunchKernelGGL(lstm_kernel, dim3(2), dim3(512), 0, stream,
                     Whh_f, Whh_b, h0, c0, Gx, out_lstm);
  hipLaunchKernelGGL(attn_kernel, dim3(16, 128), dim3(256), 0, stream,
                     out_lstm, w_omega, u_omega, logits);
  hipLaunchKernelGGL(softmax_kernel, dim3(1), dim3(1024), 0, stream, logits, alphas);
  hipLaunchKernelGGL(feats_kernel, dim3(256), dim3(256), 0, stream,
                     out_lstm, W_tag, b_tag, alphas, feats);
  hipLaunchKernelGGL(vit_block_mats, dim3(128), dim3(256), 0, stream,
                     feats, trans, Cmat);
  hipLaunchKernelGGL(vit_scan, dim3(1), dim3(64), 0, stream,
                     Cmat, trans, v_in, out, best_ws);
  hipLaunchKernelGGL(vit_bp, dim3(128), dim3(64), 0, stream,
                     feats, trans, v_in, bp);
  hipLaunchKernelGGL(vit_bmap, dim3(128), dim3(64), 0, stream, bp, Bmap);
  hipLaunchKernelGGL(vit_suffix, dim3(1), dim3(64), 0, stream, Bmap, Stail);
  hipLaunchKernelGGL(vit_emit, dim3(128), dim3(64), 0, stream,
                     bp, Stail, best_ws, out);
}